// Round 4
// baseline (419.043 us; speedup 1.0000x reference)
//
#include <hip/hip_runtime.h>

#define NFEAT 128

using bf16x8 = __attribute__((ext_vector_type(8))) short;
using f32x4  = __attribute__((ext_vector_type(4))) float;

__device__ __forceinline__ float bf2f(unsigned short u) {
    union { unsigned int i; float f; } v; v.i = ((unsigned int)u) << 16; return v.f;
}
__device__ __forceinline__ float bfhi2f(unsigned int hi16) {   // already-shifted bits
    union { unsigned int i; float f; } v; v.i = hi16; return v.f;
}
__device__ __forceinline__ unsigned short f2bf(float f) {      // RNE
    union { float f; unsigned int i; } v; v.f = f;
    unsigned int i = v.i;
    return (unsigned short)((i + 0x7FFFu + ((i >> 16) & 1u)) >> 16);
}

// ---------------- CSR build ----------------

__global__ void hist_kernel(const int* __restrict__ dst, int* __restrict__ cnt, int nE) {
    int i = blockIdx.x * blockDim.x + threadIdx.x;
    if (i < nE) atomicAdd(&cnt[dst[i]], 1);
}

__global__ void blocksum_kernel(const int* __restrict__ cnt, int* __restrict__ blockSum, int n) {
    int i = blockIdx.x * 256 + threadIdx.x;
    int d = (i < n) ? cnt[i] : 0;
    int lane = threadIdx.x & 63, wid = threadIdx.x >> 6;
    __shared__ int ws[4];
    int v = d;
    for (int off = 32; off; off >>= 1) v += __shfl_down(v, off);
    if (lane == 0) ws[wid] = v;
    __syncthreads();
    if (threadIdx.x == 0) blockSum[blockIdx.x] = ws[0] + ws[1] + ws[2] + ws[3];
}

__global__ void scan_write_kernel(int* __restrict__ cnt, const int* __restrict__ blockSum,
                                  int* __restrict__ row_ptr, float* __restrict__ inv_deg,
                                  int n) {
    const int b = blockIdx.x, tid = threadIdx.x;
    const int lane = tid & 63, wid = tid >> 6;
    __shared__ int wsA[4];
    __shared__ int wsB[4];
    int v = (tid < b) ? blockSum[tid] : 0;
    for (int off = 32; off; off >>= 1) v += __shfl_down(v, off);
    if (lane == 0) wsA[wid] = v;
    int i = b * 256 + tid;
    int d = (i < n) ? cnt[i] : 0;
    int s = d;
    for (int off = 1; off < 64; off <<= 1) {
        int t = __shfl_up(s, off);
        if (lane >= off) s += t;
    }
    if (lane == 63) wsB[wid] = s;
    __syncthreads();
    int blockOff = wsA[0] + wsA[1] + wsA[2] + wsA[3];
    int wOff = 0;
    for (int w = 0; w < wid; ++w) wOff += wsB[w];
    int excl = blockOff + wOff + s - d;
    if (i < n) {
        row_ptr[i] = excl;
        cnt[i]     = excl;
        inv_deg[i] = 1.0f / (float)(d > 1 ? d : 1);
    }
    if (i == n) row_ptr[n] = excl;
}

__global__ void fill_kernel(const int* __restrict__ src, const int* __restrict__ dst,
                            int* __restrict__ cnt, int* __restrict__ col_idx, int nE) {
    int i = blockIdx.x * blockDim.x + threadIdx.x;
    if (i < nE) {
        int pos = atomicAdd(&cnt[dst[i]], 1);
        col_idx[pos] = src[i];
    }
}

// ---------------- conversions ----------------

// x fp32 -> hi/lo bf16 planes, 4 elems/thread
__global__ void xconv_kernel(const float* __restrict__ x, unsigned short* __restrict__ xH,
                             unsigned short* __restrict__ xL, int total4) {
    int i = blockIdx.x * 256 + threadIdx.x;
    if (i >= total4) return;
    float4 v = ((const float4*)x)[i];
    unsigned short h0 = f2bf(v.x), h1 = f2bf(v.y), h2 = f2bf(v.z), h3 = f2bf(v.w);
    uint2 hw;
    hw.x = (unsigned int)h0 | ((unsigned int)h1 << 16);
    hw.y = (unsigned int)h2 | ((unsigned int)h3 << 16);
    ((uint2*)xH)[i] = hw;
    unsigned short l0 = f2bf(v.x - bf2f(h0)), l1 = f2bf(v.y - bf2f(h1));
    unsigned short l2 = f2bf(v.z - bf2f(h2)), l3 = f2bf(v.w - bf2f(h3));
    uint2 lw;
    lw.x = (unsigned int)l0 | ((unsigned int)l1 << 16);
    lw.y = (unsigned int)l2 | ((unsigned int)l3 << 16);
    ((uint2*)xL)[i] = lw;
}

// W -> transposed K-major cat [nout][256]: k<128 from Wl, else Wr; hi/lo planes.
__global__ void wconv_kernel(const float* __restrict__ Wl, const float* __restrict__ Wr,
                             unsigned short* __restrict__ WtH, unsigned short* __restrict__ WtL,
                             int nout) {
    int idx = blockIdx.x * 256 + threadIdx.x;
    if (idx >= nout * 256) return;
    int c = idx >> 8, k = idx & 255;
    float f = (k < 128) ? Wl[k * nout + c] : Wr[(k - 128) * nout + c];
    unsigned short hi = f2bf(f);
    WtH[idx] = hi;
    WtL[idx] = f2bf(f - bf2f(hi));
}

// ---------------- mean aggregation (CSR gather, bf16 hi/lo planes) ----------------
// 32 lanes per node, 4 features/lane (uint2 per plane). Unroll-by-4 independent accums.
__global__ void agg_kernel(const unsigned short* __restrict__ inH,
                           const unsigned short* __restrict__ inL,
                           const int* __restrict__ row_ptr, const int* __restrict__ col_idx,
                           const float* __restrict__ inv_deg,
                           unsigned short* __restrict__ aggH, unsigned short* __restrict__ aggL,
                           int n) {
    int lane = threadIdx.x & 31;
    int node = blockIdx.x * 8 + (threadIdx.x >> 5);
    if (node >= n) return;
    int beg = row_ptr[node], end = row_ptr[node + 1];
    float4 a0 = make_float4(0.f, 0.f, 0.f, 0.f);
    float4 a1 = make_float4(0.f, 0.f, 0.f, 0.f);
    float4 a2 = make_float4(0.f, 0.f, 0.f, 0.f);
    float4 a3 = make_float4(0.f, 0.f, 0.f, 0.f);
    auto accum = [&](float4& a, uint2 H, uint2 L) {
        a.x += bfhi2f(H.x << 16)        + bfhi2f(L.x << 16);
        a.y += bfhi2f(H.x & 0xFFFF0000u) + bfhi2f(L.x & 0xFFFF0000u);
        a.z += bfhi2f(H.y << 16)        + bfhi2f(L.y << 16);
        a.w += bfhi2f(H.y & 0xFFFF0000u) + bfhi2f(L.y & 0xFFFF0000u);
    };
    int e = beg;
    for (; e + 4 <= end; e += 4) {
        int s0 = col_idx[e], s1 = col_idx[e + 1], s2 = col_idx[e + 2], s3 = col_idx[e + 3];
        uint2 H0 = ((const uint2*)(inH + (size_t)s0 * NFEAT))[lane];
        uint2 L0 = ((const uint2*)(inL + (size_t)s0 * NFEAT))[lane];
        uint2 H1 = ((const uint2*)(inH + (size_t)s1 * NFEAT))[lane];
        uint2 L1 = ((const uint2*)(inL + (size_t)s1 * NFEAT))[lane];
        uint2 H2 = ((const uint2*)(inH + (size_t)s2 * NFEAT))[lane];
        uint2 L2 = ((const uint2*)(inL + (size_t)s2 * NFEAT))[lane];
        uint2 H3 = ((const uint2*)(inH + (size_t)s3 * NFEAT))[lane];
        uint2 L3 = ((const uint2*)(inL + (size_t)s3 * NFEAT))[lane];
        accum(a0, H0, L0); accum(a1, H1, L1); accum(a2, H2, L2); accum(a3, H3, L3);
    }
    for (; e < end; ++e) {
        int s = col_idx[e];
        uint2 H = ((const uint2*)(inH + (size_t)s * NFEAT))[lane];
        uint2 L = ((const uint2*)(inL + (size_t)s * NFEAT))[lane];
        accum(a0, H, L);
    }
    float sc = inv_deg[node];
    float v0 = (a0.x + a1.x + a2.x + a3.x) * sc;
    float v1 = (a0.y + a1.y + a2.y + a3.y) * sc;
    float v2 = (a0.z + a1.z + a2.z + a3.z) * sc;
    float v3 = (a0.w + a1.w + a2.w + a3.w) * sc;
    unsigned short h0 = f2bf(v0), h1 = f2bf(v1), h2 = f2bf(v2), h3 = f2bf(v3);
    uint2 hw;
    hw.x = (unsigned int)h0 | ((unsigned int)h1 << 16);
    hw.y = (unsigned int)h2 | ((unsigned int)h3 << 16);
    ((uint2*)(aggH + (size_t)node * NFEAT))[lane] = hw;
    unsigned short l0 = f2bf(v0 - bf2f(h0)), l1 = f2bf(v1 - bf2f(h1));
    unsigned short l2 = f2bf(v2 - bf2f(h2)), l3 = f2bf(v3 - bf2f(h3));
    uint2 lw;
    lw.x = (unsigned int)l0 | ((unsigned int)l1 << 16);
    lw.y = (unsigned int)l2 | ((unsigned int)l3 << 16);
    ((uint2*)(aggL + (size_t)node * NFEAT))[lane] = lw;
}

// ---------------- MFMA GEMM: C = [agg|x] @ [Wl;Wr] + b, split-bf16 ----------------
// K = 256 (ksteps 0-3 from agg planes, 4-7 from x planes). B (Wt, K-major
// [NOUT][256]) lives fully in registers (hi+lo = 128 VGPRs/wave); no LDS, no
// barriers. Wave tile: 32 nodes x 32 cols (2 M-frags x 2 N-frags, 16x16x32).
// 3 products per frag pair: Ah@Wh + Al@Wh + Ah@Wl (drops ~2^-18 term).

template<int NOUT, bool RELU, bool FINAL>
__global__ __launch_bounds__(256) void mfma_gemm(
    const unsigned short* __restrict__ aggH, const unsigned short* __restrict__ aggL,
    const unsigned short* __restrict__ xH,  const unsigned short* __restrict__ xL,
    const unsigned short* __restrict__ WtH, const unsigned short* __restrict__ WtL,
    const float* __restrict__ bias,
    float* __restrict__ outF, unsigned short* __restrict__ outH, unsigned short* __restrict__ outL,
    int n)
{
    constexpr int NWC = NOUT / 32;          // waves along cols (4 or 2)
    constexpr int NWR = 4 / NWC;            // waves along rows (1 or 2)
    constexpr int MT  = 32 * NWR;           // nodes per block
    const int wid  = threadIdx.x >> 6;
    const int lane = threadIdx.x & 63;
    const int wc = wid % NWC, wr = wid / NWC;
    const int colBase = wc * 32;
    const int rowBase = blockIdx.x * MT + wr * 32;
    const int lrow = lane & 15;
    const int lk   = (lane >> 4) * 8;

    // B fragments in registers
    bf16x8 bh[2][8], bl[2][8];
    #pragma unroll
    for (int nf = 0; nf < 2; ++nf) {
        const size_t cb = (size_t)(colBase + nf * 16 + lrow) * 256 + lk;
        #pragma unroll
        for (int ks = 0; ks < 8; ++ks) {
            bh[nf][ks] = *(const bf16x8*)(WtH + cb + ks * 32);
            bl[nf][ks] = *(const bf16x8*)(WtL + cb + ks * 32);
        }
    }

    int r0 = rowBase + lrow;       if (r0 > n - 1) r0 = n - 1;
    int r1 = rowBase + 16 + lrow;  if (r1 > n - 1) r1 = n - 1;

    f32x4 acc[2][2];
    #pragma unroll
    for (int mf = 0; mf < 2; ++mf)
        #pragma unroll
        for (int nf = 0; nf < 2; ++nf)
            acc[mf][nf] = (f32x4){0.f, 0.f, 0.f, 0.f};

    #pragma unroll
    for (int ks = 0; ks < 8; ++ks) {
        const unsigned short* SH = (ks < 4) ? aggH : xH;
        const unsigned short* SL = (ks < 4) ? aggL : xL;
        const int kk = (ks & 3) * 32 + lk;
        bf16x8 a0h = *(const bf16x8*)(SH + (size_t)r0 * NFEAT + kk);
        bf16x8 a1h = *(const bf16x8*)(SH + (size_t)r1 * NFEAT + kk);
        bf16x8 a0l = *(const bf16x8*)(SL + (size_t)r0 * NFEAT + kk);
        bf16x8 a1l = *(const bf16x8*)(SL + (size_t)r1 * NFEAT + kk);
        #pragma unroll
        for (int nf = 0; nf < 2; ++nf) {
            acc[0][nf] = __builtin_amdgcn_mfma_f32_16x16x32_bf16(a0h, bh[nf][ks], acc[0][nf], 0, 0, 0);
            acc[0][nf] = __builtin_amdgcn_mfma_f32_16x16x32_bf16(a0l, bh[nf][ks], acc[0][nf], 0, 0, 0);
            acc[0][nf] = __builtin_amdgcn_mfma_f32_16x16x32_bf16(a0h, bl[nf][ks], acc[0][nf], 0, 0, 0);
            acc[1][nf] = __builtin_amdgcn_mfma_f32_16x16x32_bf16(a1h, bh[nf][ks], acc[1][nf], 0, 0, 0);
            acc[1][nf] = __builtin_amdgcn_mfma_f32_16x16x32_bf16(a1l, bh[nf][ks], acc[1][nf], 0, 0, 0);
            acc[1][nf] = __builtin_amdgcn_mfma_f32_16x16x32_bf16(a1h, bl[nf][ks], acc[1][nf], 0, 0, 0);
        }
    }

    // epilogue: bias (+ReLU); FINAL -> fp32 out, else -> next-layer hi/lo planes
    #pragma unroll
    for (int mf = 0; mf < 2; ++mf) {
        #pragma unroll
        for (int nf = 0; nf < 2; ++nf) {
            const int c = colBase + nf * 16 + lrow;
            const float bv = bias[c];
            #pragma unroll
            for (int reg = 0; reg < 4; ++reg) {
                const int r = rowBase + mf * 16 + (lane >> 4) * 4 + reg;
                if (r < n) {
                    float h = acc[mf][nf][reg] + bv;
                    if (RELU) h = fmaxf(h, 0.f);
                    if (FINAL) {
                        outF[(size_t)r * NOUT + c] = h;
                    } else {
                        unsigned short hi = f2bf(h);
                        outH[(size_t)r * NFEAT + c] = hi;
                        outL[(size_t)r * NFEAT + c] = f2bf(h - bf2f(hi));
                    }
                }
            }
        }
    }
}

extern "C" void kernel_launch(void* const* d_in, const int* in_sizes, int n_in,
                              void* d_out, int out_size, void* d_ws, size_t ws_size,
                              hipStream_t stream) {
    const float* x   = (const float*)d_in[0];
    const int*   ei  = (const int*)d_in[1];
    const float* Wl0 = (const float*)d_in[2];
    const float* Wr0 = (const float*)d_in[3];
    const float* b0  = (const float*)d_in[4];
    const float* Wl1 = (const float*)d_in[5];
    const float* Wr1 = (const float*)d_in[6];
    const float* b1  = (const float*)d_in[7];
    const float* Wl2 = (const float*)d_in[8];
    const float* Wr2 = (const float*)d_in[9];
    const float* b2  = (const float*)d_in[10];

    const int nN = in_sizes[0] / NFEAT;       // 50000
    const int nE = in_sizes[1] / 2;           // 800000
    const int* src = ei;
    const int* dst = ei + nE;

    char* ws = (char*)d_ws;
    size_t off = 0;
    auto take = [&](size_t bytes) { char* p = ws + off; off += (bytes + 255) & ~(size_t)255; return p; };
    int*   cnt      = (int*)  take((size_t)nN * 4);
    int*   row_ptr  = (int*)  take((size_t)(nN + 1) * 4);
    int*   col_idx  = (int*)  take((size_t)nE * 4);
    float* inv_deg  = (float*)take((size_t)nN * 4);
    int*   blockSum = (int*)  take(256 * 4);
    const size_t plane = (size_t)nN * NFEAT * 2;           // bf16 plane bytes
    unsigned short* aggH = (unsigned short*)take(plane);
    unsigned short* aggL = (unsigned short*)take(plane);
    unsigned short* xH0  = (unsigned short*)take(plane);
    unsigned short* xL0  = (unsigned short*)take(plane);
    unsigned short* xH1  = (unsigned short*)take(plane);
    unsigned short* xL1  = (unsigned short*)take(plane);
    unsigned short* WtH0 = (unsigned short*)take(128 * 256 * 2);
    unsigned short* WtL0 = (unsigned short*)take(128 * 256 * 2);
    unsigned short* WtH1 = (unsigned short*)take(128 * 256 * 2);
    unsigned short* WtL1 = (unsigned short*)take(128 * 256 * 2);
    unsigned short* WtH2 = (unsigned short*)take(64 * 256 * 2);
    unsigned short* WtL2 = (unsigned short*)take(64 * 256 * 2);
    (void)ws_size; (void)n_in; (void)out_size;

    const int scanBlocks = (nN + 255) / 256;

    // CSR build
    hipMemsetAsync(cnt, 0, (size_t)nN * 4, stream);
    hist_kernel<<<(nE + 255) / 256, 256, 0, stream>>>(dst, cnt, nE);
    blocksum_kernel<<<scanBlocks, 256, 0, stream>>>(cnt, blockSum, nN);
    scan_write_kernel<<<scanBlocks, 256, 0, stream>>>(cnt, blockSum, row_ptr, inv_deg, nN);
    fill_kernel<<<(nE + 255) / 256, 256, 0, stream>>>(src, dst, cnt, col_idx, nE);

    // conversions
    xconv_kernel<<<(nN * NFEAT / 4 + 255) / 256, 256, 0, stream>>>(x, xH0, xL0, nN * NFEAT / 4);
    wconv_kernel<<<(128 * 256 + 255) / 256, 256, 0, stream>>>(Wl0, Wr0, WtH0, WtL0, 128);
    wconv_kernel<<<(128 * 256 + 255) / 256, 256, 0, stream>>>(Wl1, Wr1, WtH1, WtL1, 128);
    wconv_kernel<<<(64 * 256 + 255) / 256, 256, 0, stream>>>(Wl2, Wr2, WtH2, WtL2, 64);

    const int aggGrid = (nN + 7) / 8;

    // layer 0: x -> h0
    agg_kernel<<<aggGrid, 256, 0, stream>>>(xH0, xL0, row_ptr, col_idx, inv_deg, aggH, aggL, nN);
    mfma_gemm<128, true, false><<<(nN + 31) / 32, 256, 0, stream>>>(
        aggH, aggL, xH0, xL0, WtH0, WtL0, b0, nullptr, xH1, xL1, nN);
    // layer 1: h0 -> h1
    agg_kernel<<<aggGrid, 256, 0, stream>>>(xH1, xL1, row_ptr, col_idx, inv_deg, aggH, aggL, nN);
    mfma_gemm<128, true, false><<<(nN + 31) / 32, 256, 0, stream>>>(
        aggH, aggL, xH1, xL1, WtH1, WtL1, b1, nullptr, xH0, xL0, nN);
    // layer 2: h1 -> out (fp32)
    agg_kernel<<<aggGrid, 256, 0, stream>>>(xH0, xL0, row_ptr, col_idx, inv_deg, aggH, aggL, nN);
    mfma_gemm<64, false, true><<<(nN + 63) / 64, 256, 0, stream>>>(
        aggH, aggL, xH0, xL0, WtH2, WtL2, b2, (float*)d_out, nullptr, nullptr, nN);
}